// Round 1
// baseline (14352.316 us; speedup 1.0000x reference)
//
#include <hip/hip_runtime.h>
#include <math.h>

#define T_ 8
#define B_ 4
#define CIN_ 3
#define H_ 30
#define W_ 32
#define HID_ 128
#define NPOS_ (H_*W_)          // 960
#define CHW_ (HID_*NPOS_)      // 122880
#define SEQ_ (T_*B_*CHW_)      // 3932160
#define LIN1_IN_ (HID_*NPOS_)  // 122880

// Fused 3x3 SAME conv over concat[x_t, h_{t-1}] + ConvLSTM gate update.
// grid: (B_*H_, 4 channel-groups); block: 256 threads.
// Each block handles one (b, y), hid channels [cg*32, cg*32+32), all 32 x.
// Conv output channel oc = gate*128 + hid, gate 0..3 = i,f,o,g.
__global__ __launch_bounds__(256)
void convlstm_step(const float* __restrict__ xin, int CX, int CTOT,
                   const float* __restrict__ Wk, const float* __restrict__ bias,
                   const float* __restrict__ hprev,
                   float* __restrict__ hout, float* __restrict__ cbuf)
{
  const int tid = threadIdx.x;
  const int b  = blockIdx.x / H_;
  const int y  = blockIdx.x % H_;
  const int cg = blockIdx.y;

  const int ng = tid & 31;   // gate-channel quad: n = ng*4 .. ng*4+3 (n in [0,128))
  const int xg = tid >> 5;   // x quad: x = xg*4 .. xg*4+3

  // A tile: 8 cin x 3 rows x 36 cols (cols 0..33 = x=-1..32 zero-padded)
  // B tile: 8 cin x 9 taps x 132 (128 gate-channels, padded to 132 for banks)
  __shared__ __align__(16) float smem[8*3*36 + 8*9*132];
  float (*a_lds)[3][36]  = (float (*)[3][36])smem;
  float (*b_lds)[9][132] = (float (*)[9][132])(smem + 8*3*36);

  float acc[4][4];
  #pragma unroll
  for (int j = 0; j < 4; ++j)
    #pragma unroll
    for (int n = 0; n < 4; ++n) acc[j][n] = 0.f;

  for (int cbase = 0; cbase < CTOT; cbase += 8) {
    // ---- stage A: input patch ----
    for (int idx = tid; idx < 8*3*36; idx += 256) {
      int ci  = idx / (3*36);
      int rem = idx % (3*36);
      int r   = rem / 36;
      int col = rem % 36;
      int cc = cbase + ci;
      int yy = y + r - 1;
      int gx = col - 1;
      float v = 0.f;
      if (cc < CTOT && yy >= 0 && yy < H_ && gx >= 0 && gx < W_) {
        if (cc < CX)      v = xin[((b*CX + cc)*H_ + yy)*W_ + gx];
        else if (hprev)   v = hprev[((b*HID_ + (cc - CX))*H_ + yy)*W_ + gx];
        // hprev == nullptr means t==0 -> h0 = 0
      }
      a_lds[ci][r][col] = v;
    }
    // ---- stage B: weights. For fixed oc, the chunk's 8x9 = 72 floats are
    // contiguous in memory ((oc*CTOT + cbase)*9 + rem), so consecutive lanes
    // read consecutive addresses. ----
    for (int idx = tid; idx < 8*9*128; idx += 256) {
      int n   = idx / 72;
      int rem = idx % 72;    // = ci*9 + tap
      int ci  = rem / 9;
      int tap = rem % 9;
      int cc  = cbase + ci;
      float v = 0.f;
      if (cc < CTOT) {
        int gate = n >> 5, hc = n & 31;
        int oc = gate*HID_ + cg*32 + hc;
        v = Wk[(oc*CTOT + cbase)*9 + rem];
      }
      b_lds[ci][tap][n] = v;
    }
    __syncthreads();
    // ---- compute: 4x4 micro-tile per thread ----
    #pragma unroll 2
    for (int ci = 0; ci < 8; ++ci) {
      float a6[3][6];
      #pragma unroll
      for (int r = 0; r < 3; ++r)
        #pragma unroll
        for (int m = 0; m < 6; ++m)
          a6[r][m] = a_lds[ci][r][xg*4 + m];
      #pragma unroll
      for (int ky = 0; ky < 3; ++ky)
        #pragma unroll
        for (int kx = 0; kx < 3; ++kx) {
          const float4 bv = *(const float4*)&b_lds[ci][ky*3+kx][ng*4];
          #pragma unroll
          for (int j = 0; j < 4; ++j) {
            float av = a6[ky][j + kx];  // col = x + kx = xg*4 + j + kx
            acc[j][0] = fmaf(av, bv.x, acc[j][0]);
            acc[j][1] = fmaf(av, bv.y, acc[j][1]);
            acc[j][2] = fmaf(av, bv.z, acc[j][2]);
            acc[j][3] = fmaf(av, bv.w, acc[j][3]);
          }
        }
    }
    __syncthreads();
  }

  // ---- epilogue: gather 4 gates per (hc,x) via LDS, LSTM update ----
  float (*g_lds)[32][33] = (float (*)[32][33])smem;  // [gate][hc][x], padded
  {
    const int n0 = ng*4;
    const int gate = n0 >> 5;
    const int hc0 = n0 & 31;
    #pragma unroll
    for (int nn = 0; nn < 4; ++nn) {
      const float bv = bias[gate*HID_ + cg*32 + hc0 + nn];
      #pragma unroll
      for (int j = 0; j < 4; ++j)
        g_lds[gate][hc0 + nn][xg*4 + j] = acc[j][nn] + bv;
    }
  }
  __syncthreads();
  for (int cell = tid; cell < 32*32; cell += 256) {
    int hc = cell >> 5, x = cell & 31;
    float vi = g_lds[0][hc][x];
    float vf = g_lds[1][hc][x];
    float vo = g_lds[2][hc][x];
    float vg = g_lds[3][hc][x];
    float ig = 1.f / (1.f + expf(-vi));
    float fg = 1.f / (1.f + expf(-vf));
    float og = 1.f / (1.f + expf(-vo));
    float gg = tanhf(vg);
    int idx = ((b*HID_ + cg*32 + hc)*H_ + y)*W_ + x;
    float cn = fg * cbuf[idx] + ig * gg;
    cbuf[idx] = cn;
    hout[idx] = og * tanhf(cn);
  }
}

// z1[b][o] = relu(dot(h_last[b], lin1_w[o]) + lin1_b[o]); one block per o.
__global__ __launch_bounds__(256)
void lin1_kernel(const float* __restrict__ h, const float* __restrict__ w,
                 const float* __restrict__ bias, float* __restrict__ z1)
{
  const int o = blockIdx.x;       // 0..255
  const int tid = threadIdx.x;    // 256
  const float* wrow = w + (size_t)o * LIN1_IN_;
  float acc[4] = {0.f, 0.f, 0.f, 0.f};
  for (int k = tid; k < LIN1_IN_; k += 256) {
    float wv = wrow[k];
    acc[0] = fmaf(wv, h[0*LIN1_IN_ + k], acc[0]);
    acc[1] = fmaf(wv, h[1*LIN1_IN_ + k], acc[1]);
    acc[2] = fmaf(wv, h[2*LIN1_IN_ + k], acc[2]);
    acc[3] = fmaf(wv, h[3*LIN1_IN_ + k], acc[3]);
  }
  #pragma unroll
  for (int i = 0; i < 4; ++i)
    for (int m = 32; m; m >>= 1) acc[i] += __shfl_xor(acc[i], m);
  __shared__ float red[4][4];
  if ((tid & 63) == 0) {
    #pragma unroll
    for (int i = 0; i < 4; ++i) red[tid >> 6][i] = acc[i];
  }
  __syncthreads();
  if (tid == 0) {
    #pragma unroll
    for (int i = 0; i < 4; ++i) {
      float s = red[0][i] + red[1][i] + red[2][i] + red[3][i] + bias[o];
      z1[i*256 + o] = fmaxf(s, 0.f);
    }
  }
}

// z2[b][j] = dot(z1[b], lin2_w[j]) + lin2_b[j]; out = [mu(4), sigma(4)]
__global__ __launch_bounds__(64)
void lin2_kernel(const float* __restrict__ z1, const float* __restrict__ w2,
                 const float* __restrict__ b2, float* __restrict__ out)
{
  const int lane = threadIdx.x;
  for (int p = 0; p < 8; ++p) {
    int j = p >> 2, b = p & 3;       // p = j*4 + b  (mu's 4 first, then sigma's)
    float acc = 0.f;
    for (int k = lane; k < 256; k += 64)
      acc = fmaf(z1[b*256 + k], w2[j*256 + k], acc);
    for (int m = 32; m; m >>= 1) acc += __shfl_xor(acc, m);
    if (lane == 0) out[p] = acc + b2[j];
  }
}

extern "C" void kernel_launch(void* const* d_in, const int* in_sizes, int n_in,
                              void* d_out, int out_size, void* d_ws, size_t ws_size,
                              hipStream_t stream) {
  const float* x = (const float*)d_in[0];
  const float* Wks[4] = {(const float*)d_in[1], (const float*)d_in[3],
                         (const float*)d_in[5], (const float*)d_in[7]};
  const float* bks[4] = {(const float*)d_in[2], (const float*)d_in[4],
                         (const float*)d_in[6], (const float*)d_in[8]};
  const float* lin1_w = (const float*)d_in[9];
  const float* lin1_b = (const float*)d_in[10];
  const float* lin2_w = (const float*)d_in[11];
  const float* lin2_b = (const float*)d_in[12];
  float* out = (float*)d_out;

  float* seqA = (float*)d_ws;            // (T,B,128,30,32)
  float* seqB = seqA + SEQ_;             // (T,B,128,30,32)
  float* cbuf = seqB + SEQ_;             // (B,128,30,32)
  float* z1   = cbuf + (size_t)B_*CHW_;  // (B,256)

  const float* in_seq = x;
  float* out_seq = seqA;
  for (int l = 0; l < 4; ++l) {
    const int CX = (l == 0) ? CIN_ : HID_;
    const int CTOT = CX + HID_;
    hipMemsetAsync(cbuf, 0, (size_t)B_*CHW_*sizeof(float), stream);
    for (int t = 0; t < T_; ++t) {
      const float* xin = in_seq + (size_t)t * B_ * CX * NPOS_;
      const float* hprev = (t == 0) ? nullptr : out_seq + (size_t)(t-1)*B_*CHW_;
      float* hout = out_seq + (size_t)t*B_*CHW_;
      dim3 grid(B_*H_, 4);
      convlstm_step<<<grid, dim3(256), 0, stream>>>(
          xin, CX, CTOT, Wks[l], bks[l], hprev, hout, cbuf);
    }
    in_seq = out_seq;
    out_seq = (out_seq == seqA) ? seqB : seqA;
  }
  const float* h_last = in_seq + (size_t)(T_-1)*B_*CHW_;
  lin1_kernel<<<dim3(256), dim3(256), 0, stream>>>(h_last, lin1_w, lin1_b, z1);
  lin2_kernel<<<dim3(1), dim3(64), 0, stream>>>(z1, lin2_w, lin2_b, out);
}

// Round 2
// 4272.000 us; speedup vs baseline: 3.3596x; 3.3596x over previous
//
#include <hip/hip_runtime.h>
#include <math.h>

#define T_ 8
#define B_ 4
#define CIN_ 3
#define H_ 30
#define W_ 32
#define HID_ 128
#define NPOS_ (H_*W_)          // 960
#define CHW_ (HID_*NPOS_)      // 122880
#define SEQ_ (T_*B_*CHW_)      // 3932160
#define LIN1_IN_ (HID_*NPOS_)  // 122880

// ---------------------------------------------------------------------------
// One-time weight transform: Wt[k][m], k = ci*9 + (ky*3+kx) (ci zero-padded to
// NCHUNK*8), m = hid*4 + gate  (so one thread's float4 = 4 gates of one hid).
// W original: [gate*128+hid][ci][ky][kx].
// ---------------------------------------------------------------------------
__global__ __launch_bounds__(256)
void wtransform(const float* __restrict__ W, float* __restrict__ Wt,
                int CTOT, int total)
{
  int idx = blockIdx.x * 256 + threadIdx.x;
  if (idx >= total) return;
  int m = idx & 511;
  int k = idx >> 9;
  int ci = k / 9, tap = k - ci * 9;
  int hid = m >> 2, gate = m & 3;
  float v = 0.f;
  if (ci < CTOT) v = W[((gate * HID_ + hid) * CTOT + ci) * 9 + tap];
  Wt[idx] = v;
}

// ---------------------------------------------------------------------------
// Fused conv(3x3, SAME, over concat[x_t, h_{t-1}]) + ConvLSTM update.
// Grid: (8 M-tiles, B_*15 N-tiles). Block 256 threads.
// M-tile = 64 oc' = 16 hid channels x 4 gates; N-tile = 64 = 2 y-rows x 32 x.
// Thread: ng = tid&15 -> hid = mt*16+ng (4 gates in acc rows);
//         xg = tid>>4 -> 4 positions, row_local = xg>>3, x0 = (xg&7)*4.
// K streamed in chunks of 8 input channels with register prefetch.
// ---------------------------------------------------------------------------
__global__ __launch_bounds__(256)
void convlstm_step(const float* __restrict__ xin, int CX, int CTOT, int NCHUNK,
                   const float* __restrict__ Wt, const float* __restrict__ bias,
                   const float* __restrict__ hprev,
                   float* __restrict__ hout, float* __restrict__ cbuf)
{
  const int tid = threadIdx.x;
  const int mt = blockIdx.x;            // 0..7
  const int nt = blockIdx.y;            // 0..59
  const int b  = nt / 15;
  const int y0 = (nt % 15) * 2;

  const int ng = tid & 15;
  const int xg = tid >> 4;
  const int row_local = xg >> 3;        // 0 or 1
  const int x0 = (xg & 7) * 4;
  const int mbase = mt * 64;

  // LDS: B tile [72 k][64 oc'], A tile [8 ci][4 rows][36 cols] (col = x_in+1)
  __shared__ __align__(16) float sB[72 * 64];     // 4608 fl, 18.4 KB
  __shared__ __align__(16) float sA[8 * 4 * 36];  // 1152 fl,  4.6 KB

  float acc[4][4];
  #pragma unroll
  for (int g = 0; g < 4; ++g)
    #pragma unroll
    for (int j = 0; j < 4; ++j) acc[g][j] = 0.f;

  // ---- prefetch registers ----
  float4 pB0, pB1, pB2, pB3, pB4;
  float  pA0, pA1, pA2, pA3, pA4;

  const int kq = tid >> 4;              // 0..15 (B k_local base)
  const int mcol = mbase + (tid & 15) * 4;

  auto fetchA = [&](int f, int cbase) -> float {
    int ci  = f / 144;
    int rem = f - ci * 144;
    int row = rem / 36;
    int col = rem - row * 36;
    int xi = col - 1;
    int yi = y0 - 1 + row;
    int cg = cbase + ci;
    float v = 0.f;
    if (cg < CTOT && (unsigned)xi < 32u && (unsigned)yi < 30u) {
      if (cg < CX)
        v = xin[((b * CX + cg) * H_ + yi) * W_ + xi];
      else if (hprev)
        v = hprev[((b * HID_ + (cg - CX)) * H_ + yi) * W_ + xi];
    }
    return v;
  };

  #define ISSUE(ch) do {                                                   \
    const float* wb = Wt + ((size_t)((ch) * 72 + kq)) * 512 + mcol;        \
    pB0 = *(const float4*)(wb);                                            \
    pB1 = *(const float4*)(wb + 8192);                                     \
    pB2 = *(const float4*)(wb + 16384);                                    \
    pB3 = *(const float4*)(wb + 24576);                                    \
    if (tid < 128) pB4 = *(const float4*)(wb + 32768);                     \
    int cb = (ch) * 8;                                                     \
    pA0 = fetchA(tid, cb);                                                 \
    pA1 = fetchA(tid + 256, cb);                                           \
    pA2 = fetchA(tid + 512, cb);                                           \
    pA3 = fetchA(tid + 768, cb);                                           \
    if (tid < 128) pA4 = fetchA(tid + 1024, cb);                           \
  } while (0)

  #define WRITE() do {                                                     \
    float4* sB4 = (float4*)sB;                                             \
    sB4[tid]        = pB0;                                                 \
    sB4[tid + 256]  = pB1;                                                 \
    sB4[tid + 512]  = pB2;                                                 \
    sB4[tid + 768]  = pB3;                                                 \
    if (tid < 128) sB4[tid + 1024] = pB4;                                  \
    sA[tid]        = pA0;                                                  \
    sA[tid + 256]  = pA1;                                                  \
    sA[tid + 512]  = pA2;                                                  \
    sA[tid + 768]  = pA3;                                                  \
    if (tid < 128) sA[tid + 1024] = pA4;                                   \
  } while (0)

  ISSUE(0);
  WRITE();
  __syncthreads();

  for (int chunk = 0; chunk < NCHUNK; ++chunk) {
    const bool more = (chunk + 1 < NCHUNK);
    if (more) ISSUE(chunk + 1);

    // ---- compute chunk from LDS ----
    #pragma unroll 2
    for (int ci = 0; ci < 8; ++ci) {
      float4 ra[3][2];
      #pragma unroll
      for (int r = 0; r < 3; ++r) {
        const float* ap = &sA[(ci * 4 + row_local + r) * 36 + x0];
        ra[r][0] = *(const float4*)(ap);
        ra[r][1] = *(const float4*)(ap + 4);
      }
      #pragma unroll
      for (int ky = 0; ky < 3; ++ky) {
        #pragma unroll
        for (int kx = 0; kx < 3; ++kx) {
          const float4 bv = *(const float4*)&sB[(ci * 9 + ky * 3 + kx) * 64 + ng * 4];
          #pragma unroll
          for (int j = 0; j < 4; ++j) {
            const int e = j + kx;  // 0..5 window element
            const float av = (e < 4) ? ((const float*)&ra[ky][0])[e]
                                     : ((const float*)&ra[ky][1])[e - 4];
            acc[0][j] = fmaf(av, bv.x, acc[0][j]);
            acc[1][j] = fmaf(av, bv.y, acc[1][j]);
            acc[2][j] = fmaf(av, bv.z, acc[2][j]);
            acc[3][j] = fmaf(av, bv.w, acc[3][j]);
          }
        }
      }
    }

    if (more) {
      __syncthreads();
      WRITE();
      __syncthreads();
    }
  }
  #undef ISSUE
  #undef WRITE

  // ---- in-register LSTM epilogue: thread owns hid, (y, x0..x0+3) ----
  const int hid = mbase / 4 + ng;       // = mt*16 + ng
  const float bi = bias[0 * HID_ + hid];
  const float bf = bias[1 * HID_ + hid];
  const float bo = bias[2 * HID_ + hid];
  const float bg = bias[3 * HID_ + hid];
  const int y = y0 + row_local;
  const size_t base = (((size_t)b * HID_ + hid) * H_ + y) * W_ + x0;

  float4 cold = *(const float4*)&cbuf[base];
  float4 cnew, hnew;
  #pragma unroll
  for (int j = 0; j < 4; ++j) {
    float vi = acc[0][j] + bi;
    float vf = acc[1][j] + bf;
    float vo = acc[2][j] + bo;
    float vg = acc[3][j] + bg;
    float ig = 1.f / (1.f + expf(-vi));
    float fg = 1.f / (1.f + expf(-vf));
    float og = 1.f / (1.f + expf(-vo));
    float gg = tanhf(vg);
    float cprev = ((const float*)&cold)[j];
    float cn = fg * cprev + ig * gg;
    ((float*)&cnew)[j] = cn;
    ((float*)&hnew)[j] = og * tanhf(cn);
  }
  *(float4*)&cbuf[base] = cnew;
  *(float4*)&hout[base] = hnew;
}

// z1[b][o] = relu(dot(h_last[b], lin1_w[o]) + lin1_b[o]); one block per o.
__global__ __launch_bounds__(256)
void lin1_kernel(const float* __restrict__ h, const float* __restrict__ w,
                 const float* __restrict__ bias, float* __restrict__ z1)
{
  const int o = blockIdx.x;       // 0..255
  const int tid = threadIdx.x;
  const float* wrow = w + (size_t)o * LIN1_IN_;
  float acc[4] = {0.f, 0.f, 0.f, 0.f};
  for (int k = tid; k < LIN1_IN_; k += 256) {
    float wv = wrow[k];
    acc[0] = fmaf(wv, h[0 * LIN1_IN_ + k], acc[0]);
    acc[1] = fmaf(wv, h[1 * LIN1_IN_ + k], acc[1]);
    acc[2] = fmaf(wv, h[2 * LIN1_IN_ + k], acc[2]);
    acc[3] = fmaf(wv, h[3 * LIN1_IN_ + k], acc[3]);
  }
  #pragma unroll
  for (int i = 0; i < 4; ++i)
    for (int m = 32; m; m >>= 1) acc[i] += __shfl_xor(acc[i], m);
  __shared__ float red[4][4];
  if ((tid & 63) == 0) {
    #pragma unroll
    for (int i = 0; i < 4; ++i) red[tid >> 6][i] = acc[i];
  }
  __syncthreads();
  if (tid == 0) {
    #pragma unroll
    for (int i = 0; i < 4; ++i) {
      float s = red[0][i] + red[1][i] + red[2][i] + red[3][i] + bias[o];
      z1[i * 256 + o] = fmaxf(s, 0.f);
    }
  }
}

__global__ __launch_bounds__(64)
void lin2_kernel(const float* __restrict__ z1, const float* __restrict__ w2,
                 const float* __restrict__ b2, float* __restrict__ out)
{
  const int lane = threadIdx.x;
  for (int p = 0; p < 8; ++p) {
    int j = p >> 2, b = p & 3;
    float acc = 0.f;
    for (int k = lane; k < 256; k += 64)
      acc = fmaf(z1[b * 256 + k], w2[j * 256 + k], acc);
    for (int m = 32; m; m >>= 1) acc += __shfl_xor(acc, m);
    if (lane == 0) out[p] = acc + b2[j];
  }
}

extern "C" void kernel_launch(void* const* d_in, const int* in_sizes, int n_in,
                              void* d_out, int out_size, void* d_ws, size_t ws_size,
                              hipStream_t stream) {
  const float* x = (const float*)d_in[0];
  const float* Wks[4] = {(const float*)d_in[1], (const float*)d_in[3],
                         (const float*)d_in[5], (const float*)d_in[7]};
  const float* bks[4] = {(const float*)d_in[2], (const float*)d_in[4],
                         (const float*)d_in[6], (const float*)d_in[8]};
  const float* lin1_w = (const float*)d_in[9];
  const float* lin1_b = (const float*)d_in[10];
  const float* lin2_w = (const float*)d_in[11];
  const float* lin2_b = (const float*)d_in[12];
  float* out = (float*)d_out;

  // NCHUNK per layer: l0: ceil(131/8)=17, l1-3: 32.
  const int CXs[4]    = {CIN_, HID_, HID_, HID_};
  const int CTOTs[4]  = {CIN_ + HID_, 2 * HID_, 2 * HID_, 2 * HID_};
  const int NCHK[4]   = {17, 32, 32, 32};

  float* wt[4];
  float* p = (float*)d_ws;
  for (int l = 0; l < 4; ++l) {
    wt[l] = p;
    p += (size_t)NCHK[l] * 72 * 512;
  }
  float* seqA = p;                       // (T,B,128,30,32)
  float* seqB = seqA + SEQ_;
  float* cbuf = seqB + SEQ_;             // (B,128,30,32)
  float* z1   = cbuf + (size_t)B_ * CHW_;

  // one-time weight transforms
  for (int l = 0; l < 4; ++l) {
    int total = NCHK[l] * 72 * 512;
    wtransform<<<dim3((total + 255) / 256), dim3(256), 0, stream>>>(
        Wks[l], wt[l], CTOTs[l], total);
  }

  const float* in_seq = x;
  float* out_seq = seqA;
  for (int l = 0; l < 4; ++l) {
    const int CX = CXs[l];
    hipMemsetAsync(cbuf, 0, (size_t)B_ * CHW_ * sizeof(float), stream);
    for (int t = 0; t < T_; ++t) {
      const float* xin = in_seq + (size_t)t * B_ * CX * NPOS_;
      const float* hprev = (t == 0) ? nullptr : out_seq + (size_t)(t - 1) * B_ * CHW_;
      float* hout = out_seq + (size_t)t * B_ * CHW_;
      dim3 grid(8, B_ * 15);
      convlstm_step<<<grid, dim3(256), 0, stream>>>(
          xin, CX, CTOTs[l], NCHK[l], wt[l], bks[l], hprev, hout, cbuf);
    }
    in_seq = out_seq;
    out_seq = (out_seq == seqA) ? seqB : seqA;
  }
  const float* h_last = in_seq + (size_t)(T_ - 1) * B_ * CHW_;
  lin1_kernel<<<dim3(256), dim3(256), 0, stream>>>(h_last, lin1_w, lin1_b, z1);
  lin2_kernel<<<dim3(1), dim3(64), 0, stream>>>(z1, lin2_w, lin2_b, out);
}

// Round 3
// 3784.399 us; speedup vs baseline: 3.7925x; 1.1288x over previous
//
#include <hip/hip_runtime.h>
#include <math.h>

#define T_ 8
#define B_ 4
#define CIN_ 3
#define H_ 30
#define W_ 32
#define HID_ 128
#define NPOS_ (H_*W_)          // 960
#define CHW_ (HID_*NPOS_)      // 122880 (= B-slice per batch elem)
#define BCHW_ ((size_t)B_*CHW_)
#define LIN1_IN_ (HID_*NPOS_)  // 122880

// ---------------------------------------------------------------------------
// One-time weight transform: Wt[k][m], k = ci*9 + (ky*3+kx) (ci zero-padded to
// NCHUNK*8), m = hid*4 + gate. W original: [gate*128+hid][ci][ky][kx].
// ---------------------------------------------------------------------------
__global__ __launch_bounds__(256)
void wtransform(const float* __restrict__ W, float* __restrict__ Wt,
                int CTOT, int total)
{
  int idx = blockIdx.x * 256 + threadIdx.x;
  if (idx >= total) return;
  int m = idx & 511;
  int k = idx >> 9;
  int ci = k / 9, tap = k - ci * 9;
  int hid = m >> 2, gate = m & 3;
  float v = 0.f;
  if (ci < CTOT) v = W[((gate * HID_ + hid) * CTOT + ci) * 9 + tap];
  Wt[idx] = v;
}

// ---------------------------------------------------------------------------
// Diagonal-batched fused conv(3x3 SAME over concat[x,h]) + ConvLSTM update.
// grid = (8 M-tiles, 60 N-tiles, nActive layer-steps); block 256.
// Same per-block structure as R2 (proven): M-tile 64 oc' = 16 hid x 4 gates;
// N-tile 64 = 2 rows x 32 x; K in chunks of 8 cin, register prefetch.
// ---------------------------------------------------------------------------
struct StepSlot {
  const float* xin;
  const float* hprev;
  const float* Wt;
  const float* bias;
  float* hout;
  float* cbuf;
  int CX, CTOT, NCHUNK;
};
struct StepArgs { StepSlot s[4]; };

__global__ __launch_bounds__(256)
void convlstm_diag(StepArgs args)
{
  const StepSlot sl = args.s[blockIdx.z];
  const float* __restrict__ xin   = sl.xin;
  const float* __restrict__ hprev = sl.hprev;
  const float* __restrict__ Wt    = sl.Wt;
  const float* __restrict__ bias  = sl.bias;
  float* __restrict__ hout = sl.hout;
  float* __restrict__ cbuf = sl.cbuf;
  const int CX = sl.CX, CTOT = sl.CTOT, NCHUNK = sl.NCHUNK;

  const int tid = threadIdx.x;
  const int mt = blockIdx.x;            // 0..7
  const int nt = blockIdx.y;            // 0..59
  const int b  = nt / 15;
  const int y0 = (nt % 15) * 2;

  const int ng = tid & 15;
  const int xg = tid >> 4;
  const int row_local = xg >> 3;        // 0 or 1
  const int x0 = (xg & 7) * 4;
  const int mbase = mt * 64;

  __shared__ __align__(16) float sB[72 * 64];
  __shared__ __align__(16) float sA[8 * 4 * 36];

  float acc[4][4];
  #pragma unroll
  for (int g = 0; g < 4; ++g)
    #pragma unroll
    for (int j = 0; j < 4; ++j) acc[g][j] = 0.f;

  float4 pB0, pB1, pB2, pB3, pB4;
  float  pA0, pA1, pA2, pA3, pA4;

  const int kq = tid >> 4;
  const int mcol = mbase + (tid & 15) * 4;

  auto fetchA = [&](int f, int cbase) -> float {
    int ci  = f / 144;
    int rem = f - ci * 144;
    int row = rem / 36;
    int col = rem - row * 36;
    int xi = col - 1;
    int yi = y0 - 1 + row;
    int cg = cbase + ci;
    float v = 0.f;
    if (cg < CTOT && (unsigned)xi < 32u && (unsigned)yi < 30u) {
      if (cg < CX)
        v = xin[((b * CX + cg) * H_ + yi) * W_ + xi];
      else if (hprev)
        v = hprev[((b * HID_ + (cg - CX)) * H_ + yi) * W_ + xi];
    }
    return v;
  };

  #define ISSUE(ch) do {                                                   \
    const float* wb = Wt + ((size_t)((ch) * 72 + kq)) * 512 + mcol;        \
    pB0 = *(const float4*)(wb);                                            \
    pB1 = *(const float4*)(wb + 8192);                                     \
    pB2 = *(const float4*)(wb + 16384);                                    \
    pB3 = *(const float4*)(wb + 24576);                                    \
    if (tid < 128) pB4 = *(const float4*)(wb + 32768);                     \
    int cb = (ch) * 8;                                                     \
    pA0 = fetchA(tid, cb);                                                 \
    pA1 = fetchA(tid + 256, cb);                                           \
    pA2 = fetchA(tid + 512, cb);                                           \
    pA3 = fetchA(tid + 768, cb);                                           \
    if (tid < 128) pA4 = fetchA(tid + 1024, cb);                           \
  } while (0)

  #define WRITE() do {                                                     \
    float4* sB4 = (float4*)sB;                                             \
    sB4[tid]        = pB0;                                                 \
    sB4[tid + 256]  = pB1;                                                 \
    sB4[tid + 512]  = pB2;                                                 \
    sB4[tid + 768]  = pB3;                                                 \
    if (tid < 128) sB4[tid + 1024] = pB4;                                  \
    sA[tid]        = pA0;                                                  \
    sA[tid + 256]  = pA1;                                                  \
    sA[tid + 512]  = pA2;                                                  \
    sA[tid + 768]  = pA3;                                                  \
    if (tid < 128) sA[tid + 1024] = pA4;                                   \
  } while (0)

  ISSUE(0);
  WRITE();
  __syncthreads();

  for (int chunk = 0; chunk < NCHUNK; ++chunk) {
    const bool more = (chunk + 1 < NCHUNK);
    if (more) ISSUE(chunk + 1);

    #pragma unroll 2
    for (int ci = 0; ci < 8; ++ci) {
      float4 ra[3][2];
      #pragma unroll
      for (int r = 0; r < 3; ++r) {
        const float* ap = &sA[(ci * 4 + row_local + r) * 36 + x0];
        ra[r][0] = *(const float4*)(ap);
        ra[r][1] = *(const float4*)(ap + 4);
      }
      #pragma unroll
      for (int ky = 0; ky < 3; ++ky) {
        #pragma unroll
        for (int kx = 0; kx < 3; ++kx) {
          const float4 bv = *(const float4*)&sB[(ci * 9 + ky * 3 + kx) * 64 + ng * 4];
          #pragma unroll
          for (int j = 0; j < 4; ++j) {
            const int e = j + kx;
            const float av = (e < 4) ? ((const float*)&ra[ky][0])[e]
                                     : ((const float*)&ra[ky][1])[e - 4];
            acc[0][j] = fmaf(av, bv.x, acc[0][j]);
            acc[1][j] = fmaf(av, bv.y, acc[1][j]);
            acc[2][j] = fmaf(av, bv.z, acc[2][j]);
            acc[3][j] = fmaf(av, bv.w, acc[3][j]);
          }
        }
      }
    }

    if (more) {
      __syncthreads();
      WRITE();
      __syncthreads();
    }
  }
  #undef ISSUE
  #undef WRITE

  // in-register LSTM epilogue: thread owns hid, (y, x0..x0+3)
  const int hid = mbase / 4 + ng;
  const float bi = bias[0 * HID_ + hid];
  const float bf = bias[1 * HID_ + hid];
  const float bo = bias[2 * HID_ + hid];
  const float bg = bias[3 * HID_ + hid];
  const int y = y0 + row_local;
  const size_t base = (((size_t)b * HID_ + hid) * H_ + y) * W_ + x0;

  float4 cold = *(const float4*)&cbuf[base];
  float4 cnew, hnew;
  #pragma unroll
  for (int j = 0; j < 4; ++j) {
    float vi = acc[0][j] + bi;
    float vf = acc[1][j] + bf;
    float vo = acc[2][j] + bo;
    float vg = acc[3][j] + bg;
    float ig = 1.f / (1.f + expf(-vi));
    float fg = 1.f / (1.f + expf(-vf));
    float og = 1.f / (1.f + expf(-vo));
    float gg = tanhf(vg);
    float cprev = ((const float*)&cold)[j];
    float cn = fg * cprev + ig * gg;
    ((float*)&cnew)[j] = cn;
    ((float*)&hnew)[j] = og * tanhf(cn);
  }
  *(float4*)&cbuf[base] = cnew;
  *(float4*)&hout[base] = hnew;
}

// ---------------------------------------------------------------------------
// lin1 split-K: grid 2048 = 256 outputs x 8 K-slices; block 256; float4 loads.
// part[b][o][ks] partial sums; lin1_finish reduces + bias + relu.
// ---------------------------------------------------------------------------
__global__ __launch_bounds__(256)
void lin1_part(const float* __restrict__ h, const float* __restrict__ w,
               float* __restrict__ part)
{
  const int bid = blockIdx.x;
  const int o  = bid >> 3;
  const int ks = bid & 7;
  const int tid = threadIdx.x;
  const float4* w4 = (const float4*)(w + (size_t)o * LIN1_IN_) + ks * 3840;
  const float4* h4 = (const float4*)h + ks * 3840;
  float acc[4] = {0.f, 0.f, 0.f, 0.f};
  for (int i = tid; i < 3840; i += 256) {
    float4 wv = w4[i];
    #pragma unroll
    for (int b = 0; b < 4; ++b) {
      float4 hv = h4[(size_t)b * 30720 + i];
      acc[b] = fmaf(wv.x, hv.x, fmaf(wv.y, hv.y,
               fmaf(wv.z, hv.z, fmaf(wv.w, hv.w, acc[b]))));
    }
  }
  #pragma unroll
  for (int b = 0; b < 4; ++b)
    for (int m = 32; m; m >>= 1) acc[b] += __shfl_xor(acc[b], m);
  __shared__ float red[4][4];
  if ((tid & 63) == 0) {
    #pragma unroll
    for (int b = 0; b < 4; ++b) red[tid >> 6][b] = acc[b];
  }
  __syncthreads();
  if (tid == 0) {
    #pragma unroll
    for (int b = 0; b < 4; ++b) {
      float s = red[0][b] + red[1][b] + red[2][b] + red[3][b];
      part[((size_t)b * 256 + o) * 8 + ks] = s;
    }
  }
}

__global__ __launch_bounds__(256)
void lin1_finish(const float* __restrict__ part, const float* __restrict__ bias,
                 float* __restrict__ z1)
{
  int i = blockIdx.x * 256 + threadIdx.x;   // 0..1023 (= b*256 + o)
  if (i < 1024) {
    int o = i & 255;
    float s = bias[o];
    #pragma unroll
    for (int k = 0; k < 8; ++k) s += part[(size_t)i * 8 + k];
    z1[i] = fmaxf(s, 0.f);
  }
}

__global__ __launch_bounds__(64)
void lin2_kernel(const float* __restrict__ z1, const float* __restrict__ w2,
                 const float* __restrict__ b2, float* __restrict__ out)
{
  const int lane = threadIdx.x;
  for (int p = 0; p < 8; ++p) {
    int j = p >> 2, b = p & 3;
    float acc = 0.f;
    for (int k = lane; k < 256; k += 64)
      acc = fmaf(z1[b * 256 + k], w2[j * 256 + k], acc);
    for (int m = 32; m; m >>= 1) acc += __shfl_xor(acc, m);
    if (lane == 0) out[p] = acc + b2[j];
  }
}

extern "C" void kernel_launch(void* const* d_in, const int* in_sizes, int n_in,
                              void* d_out, int out_size, void* d_ws, size_t ws_size,
                              hipStream_t stream) {
  const float* x = (const float*)d_in[0];
  const float* Wks[4] = {(const float*)d_in[1], (const float*)d_in[3],
                         (const float*)d_in[5], (const float*)d_in[7]};
  const float* bks[4] = {(const float*)d_in[2], (const float*)d_in[4],
                         (const float*)d_in[6], (const float*)d_in[8]};
  const float* lin1_w = (const float*)d_in[9];
  const float* lin1_b = (const float*)d_in[10];
  const float* lin2_w = (const float*)d_in[11];
  const float* lin2_b = (const float*)d_in[12];
  float* out = (float*)d_out;

  const int CXs[4]   = {CIN_, HID_, HID_, HID_};
  const int CTOTs[4] = {CIN_ + HID_, 2 * HID_, 2 * HID_, 2 * HID_};
  const int NCHK[4]  = {17, 32, 32, 32};

  float* p = (float*)d_ws;
  float* wt[4];
  for (int l = 0; l < 4; ++l) { wt[l] = p; p += (size_t)NCHK[l] * 72 * 512; }
  float* ring[4];
  for (int l = 0; l < 4; ++l) { ring[l] = p; p += 2 * BCHW_; }
  float* cbase = p; p += 4 * BCHW_;     // per-layer c buffers, contiguous
  float* part = p; p += 4 * 256 * 8;
  float* z1 = p; p += 1024;

  // one-time weight transforms
  for (int l = 0; l < 4; ++l) {
    int total = NCHK[l] * 72 * 512;
    wtransform<<<dim3((total + 255) / 256), dim3(256), 0, stream>>>(
        Wks[l], wt[l], CTOTs[l], total);
  }
  // zero all c buffers in one shot
  hipMemsetAsync(cbase, 0, 4 * BCHW_ * sizeof(float), stream);

  // diagonal wavefront over (layer, t): d = l + t, d = 0..10
  for (int d = 0; d <= 10; ++d) {
    StepArgs a;
    int n = 0;
    for (int l = 0; l < 4; ++l) {
      int t = d - l;
      if (t < 0 || t > 7) continue;
      StepSlot& s = a.s[n++];
      s.CX = CXs[l]; s.CTOT = CTOTs[l]; s.NCHUNK = NCHK[l];
      s.Wt = wt[l];  s.bias = bks[l];
      s.xin = (l == 0) ? x + (size_t)t * B_ * CIN_ * NPOS_
                       : ring[l - 1] + (size_t)(t & 1) * BCHW_;
      s.hprev = (t == 0) ? nullptr : ring[l] + (size_t)((t - 1) & 1) * BCHW_;
      s.hout = ring[l] + (size_t)(t & 1) * BCHW_;
      s.cbuf = cbase + (size_t)l * BCHW_;
    }
    for (int z = n; z < 4; ++z) a.s[z] = a.s[0];  // defined-but-unused
    convlstm_diag<<<dim3(8, 60, n), dim3(256), 0, stream>>>(a);
  }

  // h_last = layer 3, t = 7 -> ring slot (7&1)=1
  const float* h_last = ring[3] + BCHW_;
  lin1_part<<<dim3(2048), dim3(256), 0, stream>>>(h_last, lin1_w, part);
  lin1_finish<<<dim3(4), dim3(256), 0, stream>>>(part, lin1_b, z1);
  lin2_kernel<<<dim3(1), dim3(64), 0, stream>>>(z1, lin2_w, lin2_b, out);
}

// Round 4
// 3359.899 us; speedup vs baseline: 4.2717x; 1.1263x over previous
//
#include <hip/hip_runtime.h>
#include <math.h>

#define T_ 8
#define B_ 4
#define CIN_ 3
#define H_ 30
#define W_ 32
#define HID_ 128
#define NPOS_ (H_*W_)          // 960
#define CHW_ (HID_*NPOS_)      // 122880
#define BCHW_ ((size_t)B_*CHW_)
#define LIN1_IN_ (HID_*NPOS_)  // 122880

typedef __attribute__((ext_vector_type(8))) short bs8;
typedef __attribute__((ext_vector_type(4))) float f32x4;

__device__ __forceinline__ unsigned short f2bf(float f) {
  unsigned u = __float_as_uint(f);
  return (unsigned short)((u + 0x7fffu + ((u >> 16) & 1u)) >> 16);
}
__device__ __forceinline__ float bf2f(unsigned short h) {
  return __uint_as_float(((unsigned)h) << 16);
}
__device__ __forceinline__ void split3(float v, unsigned short& h,
                                       unsigned short& m, unsigned short& l) {
  h = f2bf(v);
  float r = v - bf2f(h);      // exact
  m = f2bf(r);
  float r2 = r - bf2f(m);     // exact
  l = f2bf(r2);
}

// ---------------------------------------------------------------------------
// One-time weight split-transform into MFMA A-fragment layout:
// Wsp[phase=ks*9+tap][mt][split][kg4][oc128][ci8] bf16, oc' = hid*4+gate.
// ---------------------------------------------------------------------------
__global__ __launch_bounds__(256)
void wsplit(const float* __restrict__ W, unsigned short* __restrict__ Wsp,
            int CTOT, int ci_off, int total)
{
  int i = blockIdx.x * 256 + threadIdx.x;
  if (i >= total) return;
  int ci8 = i & 7;
  int oc  = (i >> 3) & 127;
  int kg  = (i >> 10) & 3;
  int mtl = (i >> 12) & 3;
  int r   = i >> 14;            // phase = ks*9 + tap
  int tap = r % 9;
  int ks  = r / 9;
  int ocp = mtl * 128 + oc;
  int hid = ocp >> 2, gate = ocp & 3;
  int cio = ci_off + ks * 32 + kg * 8 + ci8;
  float v = W[((size_t)(gate * HID_ + hid) * CTOT + cio) * 9 + tap];
  unsigned short h, m, l;
  split3(v, h, m, l);
  size_t base = ((size_t)(r * 4 + mtl) * 3) * 4096 + kg * 1024 + oc * 8 + ci8;
  Wsp[base] = h; Wsp[base + 4096] = m; Wsp[base + 8192] = l;
}

// Layer-0 x-part weights: Wxp[oc'(512)][ci3*9+tap] fp32
__global__ __launch_bounds__(256)
void wtx(const float* __restrict__ W0, float* __restrict__ Wxp)
{
  int i = blockIdx.x * 256 + threadIdx.x;
  if (i >= 512 * 27) return;
  int ocp = i / 27, rem = i % 27;
  int ci = rem / 9, tap = rem % 9;
  int hid = ocp >> 2, gate = ocp & 3;
  Wxp[i] = W0[((size_t)(gate * HID_ + hid) * 131 + ci) * 9 + tap];
}

// ---------------------------------------------------------------------------
// Split-bf16 MFMA fused conv + ConvLSTM. grid (4 mt, 60 nt, n steps), 256 thr.
// Block tile M=128 oc', N=64 pos (2 rows x 32 x). Waves 2Mx2N.
// ---------------------------------------------------------------------------
struct StepSlot {
  const float* xsrc; const float* hsrc; const float* xraw;
  const unsigned short* Wsp; const float* Wxp; const float* bias;
  float* hout; float* cbuf; int nchunk; int is_l0;
};
struct StepArgs { StepSlot s[4]; };

__global__ __launch_bounds__(256, 2)
void conv_mfma(StepArgs args)
{
  const StepSlot sl = args.s[blockIdx.z];
  const int tid = threadIdx.x;
  const int mt = blockIdx.x;            // 0..3
  const int nt = blockIdx.y;            // 0..59
  const int b  = nt / 15;
  const int y0 = (nt % 15) * 2;
  const int lane = tid & 63;
  const int wid = tid >> 6;
  const int wm = wid >> 1;              // wave M half
  const int wn = wid & 1;               // wave row
  const int lanelo = lane & 15;
  const int kgl = lane >> 4;

  // sact: [split3][row4][kg4][36 col][8 ci] bf16 = 13824 elems (27648 B)
  // sW:   2 x [split3][kg4][oc128][8 ci] bf16 = 2 x 12288    (49152 B)
  __shared__ __align__(16) unsigned short sact[13824];
  __shared__ __align__(16) unsigned short sW[2][12288];

  f32x4 acc[4][2];
  #pragma unroll
  for (int mf = 0; mf < 4; ++mf)
    #pragma unroll
    for (int nf = 0; nf < 2; ++nf)
      acc[mf][nf] = (f32x4){0.f, 0.f, 0.f, 0.f};

  // zero halo columns (x=-1 -> col0, x=32 -> col33) once
  if (tid < 96) {
    int cidx = (tid & 1) ? 33 : 0;
    int rem = tid >> 1;                 // [sp3][r4][kg4]
    int kg = rem & 3, r = (rem >> 2) & 3, sp = rem >> 4;
    unsigned short* p = &sact[(((sp * 4 + r) * 4 + kg) * 36 + cidx) * 8];
    #pragma unroll
    for (int q = 0; q < 8; ++q) p[q] = 0;
  }

  // ---- layer-0 x-part (CIN=3) VALU pass ----
  if (sl.is_l0) {
    float* sWx = (float*)&sW[0][0];     // 13824 B, aliases sW[0]
    for (int p = tid; p < 128 * 27; p += 256)
      sWx[p] = sl.Wxp[(size_t)mt * 128 * 27 + p];
    __syncthreads();
    const int y = y0 + wn;
    #pragma unroll
    for (int nf = 0; nf < 2; ++nf) {
      const int x = nf * 16 + lanelo;
      float xw[3][3][3];
      #pragma unroll
      for (int ci = 0; ci < 3; ++ci)
        #pragma unroll
        for (int ky = 0; ky < 3; ++ky)
          #pragma unroll
          for (int kx = 0; kx < 3; ++kx) {
            int yy = y + ky - 1, xx = x + kx - 1;
            xw[ci][ky][kx] = ((unsigned)yy < 30u && (unsigned)xx < 32u)
                ? sl.xraw[((size_t)(b * 3 + ci) * H_ + yy) * W_ + xx] : 0.f;
          }
      #pragma unroll
      for (int mf = 0; mf < 4; ++mf)
        #pragma unroll
        for (int g = 0; g < 4; ++g) {
          int oc = wm * 64 + mf * 16 + (kgl << 2) + g;
          float s = 0.f;
          #pragma unroll
          for (int ci = 0; ci < 3; ++ci)
            #pragma unroll
            for (int kk = 0; kk < 9; ++kk)
              s = fmaf(sWx[oc * 27 + ci * 9 + kk], xw[ci][kk / 3][kk % 3], s);
          acc[mf][nf][g] += s;
        }
    }
    __syncthreads();
  }

  const int NCH = sl.nchunk;

  auto stageAct = [&](int c) {
    const float* src = sl.is_l0 ? sl.hsrc : (c < 4 ? sl.xsrc : sl.hsrc);
    const int ci0 = (c & 3) * 32;
    const int pair = tid >> 1;
    const int xh = (tid & 1) * 16;
    const int r = pair >> 5;            // 0..3 input row
    const int ci = pair & 31;
    const int yy = y0 - 1 + r;
    float vals[16];
    if ((unsigned)yy < 30u) {
      const float* sp = src + ((size_t)(b * HID_ + ci0 + ci) * H_ + yy) * W_ + xh;
      #pragma unroll
      for (int q = 0; q < 4; ++q) {
        float4 v = *(const float4*)(sp + q * 4);
        vals[q * 4 + 0] = v.x; vals[q * 4 + 1] = v.y;
        vals[q * 4 + 2] = v.z; vals[q * 4 + 3] = v.w;
      }
    } else {
      #pragma unroll
      for (int j = 0; j < 16; ++j) vals[j] = 0.f;
    }
    const int kg = ci >> 3, cl = ci & 7;
    const int rowbase = (r * 4 + kg) * 36 * 8 + cl;
    #pragma unroll
    for (int j = 0; j < 16; ++j) {
      unsigned short hh, mm, ll;
      split3(vals[j], hh, mm, ll);
      int o = rowbase + (xh + j + 1) * 8;
      sact[o] = hh; sact[o + 4608] = mm; sact[o + 9216] = ll;
    }
  };

  if (NCH > 0) {
    { // prologue: weights phase 0 -> sW[0]; act chunk 0
      const uint4* s4 = (const uint4*)(sl.Wsp + (size_t)mt * 12288);
      uint4* d4 = (uint4*)&sW[0][0];
      #pragma unroll
      for (int p = 0; p < 6; ++p) d4[tid + p * 256] = s4[tid + p * 256];
      stageAct(0);
    }
    __syncthreads();

    for (int c = 0; c < NCH; ++c) {
      for (int tap = 0; tap < 9; ++tap) {
        const int ph = c * 9 + tap;
        const bool more = (ph + 1 < NCH * 9);
        uint4 wreg[6];
        if (more) {
          const uint4* s4 = (const uint4*)(sl.Wsp + ((size_t)(ph + 1) * 4 + mt) * 12288);
          #pragma unroll
          for (int p = 0; p < 6; ++p) wreg[p] = s4[tid + p * 256];
        }
        { // MFMA on buffer ph&1
          const int ky = tap / 3, kx = tap % 3;
          const bs8* Aw = (const bs8*)&sW[ph & 1][0];
          const bs8* Bv = (const bs8*)sact;
          bs8 Af[3][4], Bf[3][2];
          #pragma unroll
          for (int s = 0; s < 3; ++s) {
            #pragma unroll
            for (int mf = 0; mf < 4; ++mf)
              Af[s][mf] = Aw[(s * 4 + kgl) * 128 + wm * 64 + mf * 16 + lanelo];
            #pragma unroll
            for (int nf = 0; nf < 2; ++nf)
              Bf[s][nf] = Bv[((s * 4 + wn + ky) * 4 + kgl) * 36 + nf * 16 + lanelo + kx];
          }
          #define PRODUCT(SA, SB)                                              \
            _Pragma("unroll")                                                  \
            for (int mf = 0; mf < 4; ++mf) {                                   \
              _Pragma("unroll")                                                \
              for (int nf = 0; nf < 2; ++nf)                                   \
                acc[mf][nf] = __builtin_amdgcn_mfma_f32_16x16x32_bf16(         \
                    Af[SA][mf], Bf[SB][nf], acc[mf][nf], 0, 0, 0);             \
            }
          PRODUCT(0, 0) PRODUCT(0, 1) PRODUCT(1, 0)
          PRODUCT(0, 2) PRODUCT(2, 0) PRODUCT(1, 1)
          #undef PRODUCT
        }
        if (more) {
          uint4* d4 = (uint4*)&sW[(ph + 1) & 1][0];
          #pragma unroll
          for (int p = 0; p < 6; ++p) d4[tid + p * 256] = wreg[p];
        }
        __syncthreads();
      }
      if (c + 1 < NCH) {
        stageAct(c + 1);
        __syncthreads();
      }
    }
  }

  // ---- in-register LSTM epilogue ----
  #pragma unroll
  for (int mf = 0; mf < 4; ++mf) {
    const int m = wm * 64 + mf * 16 + (kgl << 2);
    const int hid = mt * 32 + (m >> 2);
    const float b0 = sl.bias[hid];
    const float b1 = sl.bias[128 + hid];
    const float b2 = sl.bias[256 + hid];
    const float b3 = sl.bias[384 + hid];
    #pragma unroll
    for (int nf = 0; nf < 2; ++nf) {
      const int x = nf * 16 + lanelo;
      const int y = y0 + wn;
      const size_t idx = ((size_t)(b * HID_ + hid) * H_ + y) * W_ + x;
      float vi = acc[mf][nf][0] + b0;
      float vf = acc[mf][nf][1] + b1;
      float vo = acc[mf][nf][2] + b2;
      float vg = acc[mf][nf][3] + b3;
      float ig = 1.f / (1.f + expf(-vi));
      float fg = 1.f / (1.f + expf(-vf));
      float og = 1.f / (1.f + expf(-vo));
      float gg = tanhf(vg);
      float cn = fg * sl.cbuf[idx] + ig * gg;
      sl.cbuf[idx] = cn;
      sl.hout[idx] = og * tanhf(cn);
    }
  }
}

// ---------------------------------------------------------------------------
// lin1 split-K (unchanged from R3), lin2
// ---------------------------------------------------------------------------
__global__ __launch_bounds__(256)
void lin1_part(const float* __restrict__ h, const float* __restrict__ w,
               float* __restrict__ part)
{
  const int bid = blockIdx.x;
  const int o  = bid >> 3;
  const int ks = bid & 7;
  const int tid = threadIdx.x;
  const float4* w4 = (const float4*)(w + (size_t)o * LIN1_IN_) + ks * 3840;
  const float4* h4 = (const float4*)h + ks * 3840;
  float acc[4] = {0.f, 0.f, 0.f, 0.f};
  for (int i = tid; i < 3840; i += 256) {
    float4 wv = w4[i];
    #pragma unroll
    for (int b = 0; b < 4; ++b) {
      float4 hv = h4[(size_t)b * 30720 + i];
      acc[b] = fmaf(wv.x, hv.x, fmaf(wv.y, hv.y,
               fmaf(wv.z, hv.z, fmaf(wv.w, hv.w, acc[b]))));
    }
  }
  #pragma unroll
  for (int b = 0; b < 4; ++b)
    for (int m = 32; m; m >>= 1) acc[b] += __shfl_xor(acc[b], m);
  __shared__ float red[4][4];
  if ((tid & 63) == 0) {
    #pragma unroll
    for (int b = 0; b < 4; ++b) red[tid >> 6][b] = acc[b];
  }
  __syncthreads();
  if (tid == 0) {
    #pragma unroll
    for (int b = 0; b < 4; ++b) {
      float s = red[0][b] + red[1][b] + red[2][b] + red[3][b];
      part[((size_t)b * 256 + o) * 8 + ks] = s;
    }
  }
}

__global__ __launch_bounds__(256)
void lin1_finish(const float* __restrict__ part, const float* __restrict__ bias,
                 float* __restrict__ z1)
{
  int i = blockIdx.x * 256 + threadIdx.x;
  if (i < 1024) {
    int o = i & 255;
    float s = bias[o];
    #pragma unroll
    for (int k = 0; k < 8; ++k) s += part[(size_t)i * 8 + k];
    z1[i] = fmaxf(s, 0.f);
  }
}

__global__ __launch_bounds__(64)
void lin2_kernel(const float* __restrict__ z1, const float* __restrict__ w2,
                 const float* __restrict__ b2, float* __restrict__ out)
{
  const int lane = threadIdx.x;
  for (int p = 0; p < 8; ++p) {
    int j = p >> 2, b = p & 3;
    float acc = 0.f;
    for (int k = lane; k < 256; k += 64)
      acc = fmaf(z1[b * 256 + k], w2[j * 256 + k], acc);
    for (int m = 32; m; m >>= 1) acc += __shfl_xor(acc, m);
    if (lane == 0) out[p] = acc + b2[j];
  }
}

extern "C" void kernel_launch(void* const* d_in, const int* in_sizes, int n_in,
                              void* d_out, int out_size, void* d_ws, size_t ws_size,
                              hipStream_t stream) {
  const float* x = (const float*)d_in[0];
  const float* Wks[4] = {(const float*)d_in[1], (const float*)d_in[3],
                         (const float*)d_in[5], (const float*)d_in[7]};
  const float* bks[4] = {(const float*)d_in[2], (const float*)d_in[4],
                         (const float*)d_in[6], (const float*)d_in[8]};
  const float* lin1_w = (const float*)d_in[9];
  const float* lin1_b = (const float*)d_in[10];
  const float* lin2_w = (const float*)d_in[11];
  const float* lin2_b = (const float*)d_in[12];
  float* out = (float*)d_out;

  const int CTOTs[4] = {131, 256, 256, 256};
  const int NKS[4]   = {4, 8, 8, 8};       // 32-ci K-steps in Wsp

  // ---- workspace carve (bf16 first, then fp32) ----
  unsigned short* wsp[4];
  unsigned short* up = (unsigned short*)d_ws;
  for (int l = 0; l < 4; ++l) {
    wsp[l] = up;
    up += (size_t)NKS[l] * 9 * 4 * 3 * 4096;
  }
  float* fp = (float*)up;
  float* wxp = fp;   fp += 512 * 27;
  float* ring[4];
  for (int l = 0; l < 4; ++l) { ring[l] = fp; fp += 2 * BCHW_; }
  float* cbase = fp; fp += 4 * BCHW_;
  float* part = fp;  fp += 4 * 256 * 8;
  float* z1 = fp;    fp += 1024;

  // ---- one-time weight transforms ----
  wtx<<<dim3(54), dim3(256), 0, stream>>>(Wks[0], wxp);
  for (int l = 0; l < 4; ++l) {
    int total = NKS[l] * 9 * 4 * 4096;
    wsplit<<<dim3((total + 255) / 256), dim3(256), 0, stream>>>(
        Wks[l], wsp[l], CTOTs[l], (l == 0) ? 3 : 0, total);
  }
  hipMemsetAsync(cbase, 0, 4 * BCHW_ * sizeof(float), stream);

  // ---- diagonal wavefront over (layer, t) ----
  for (int d = 0; d <= 10; ++d) {
    StepArgs a;
    int n = 0;
    for (int l = 0; l < 4; ++l) {
      int t = d - l;
      if (t < 0 || t > 7) continue;
      StepSlot& s = a.s[n++];
      s.is_l0 = (l == 0);
      s.Wsp = wsp[l];
      s.Wxp = (l == 0) ? wxp : nullptr;
      s.bias = bks[l];
      s.xraw = (l == 0) ? x + (size_t)t * B_ * CIN_ * NPOS_ : nullptr;
      s.xsrc = (l == 0) ? nullptr : ring[l - 1] + (size_t)(t & 1) * BCHW_;
      s.hsrc = (t == 0) ? nullptr : ring[l] + (size_t)((t - 1) & 1) * BCHW_;
      s.hout = ring[l] + (size_t)(t & 1) * BCHW_;
      s.cbuf = cbase + (size_t)l * BCHW_;
      s.nchunk = (l == 0) ? (t ? 4 : 0) : (t ? 8 : 4);
    }
    for (int z = n; z < 4; ++z) a.s[z] = a.s[0];
    conv_mfma<<<dim3(4, 60, n), dim3(256), 0, stream>>>(a);
  }

  const float* h_last = ring[3] + BCHW_;   // layer 3, t=7 -> slot 1
  lin1_part<<<dim3(2048), dim3(256), 0, stream>>>(h_last, lin1_w, part);
  lin1_finish<<<dim3(4), dim3(256), 0, stream>>>(part, lin1_b, z1);
  lin2_kernel<<<dim3(1), dim3(64), 0, stream>>>(z1, lin2_w, lin2_b, out);
}

// Round 5
// 1707.981 us; speedup vs baseline: 8.4031x; 1.9672x over previous
//
#include <hip/hip_runtime.h>
#include <math.h>

#define T_ 8
#define B_ 4
#define CIN_ 3
#define H_ 30
#define W_ 32
#define HID_ 128
#define NPOS_ (H_*W_)          // 960
#define CHW_ (HID_*NPOS_)      // 122880
#define BCHW_ ((size_t)B_*CHW_)
#define LIN1_IN_ (HID_*NPOS_)  // 122880

// hsplit global layout (shorts): [b4][split3][chunk4][y32][kg4][col34][ci8]
// y is padded: row y corresponds to unpadded y-1; rows 0,31 and cols 0,33 stay 0.
#define HS_ROW_ 1088           // kg4*col34*ci8
#define HS_CH_  34816          // 32*HS_ROW_
#define HS_SP_  139264         // 4*HS_CH_
#define HS_B_   417792         // 3*HS_SP_
#define HS_SLOT_ 1671168       // 4*HS_B_

typedef __attribute__((ext_vector_type(8))) short bs8;
typedef __attribute__((ext_vector_type(4))) float f32x4;
typedef unsigned int __attribute__((address_space(1))) gas_u32;
typedef unsigned int __attribute__((address_space(3))) las_u32;

__device__ __forceinline__ void gload16(const void* g, void* l) {
  __builtin_amdgcn_global_load_lds((const gas_u32*)g, (las_u32*)l, 16, 0, 0);
}

__device__ __forceinline__ unsigned short f2bf(float f) {
  unsigned u = __float_as_uint(f);
  return (unsigned short)((u + 0x7fffu + ((u >> 16) & 1u)) >> 16);
}
__device__ __forceinline__ float bf2f(unsigned short h) {
  return __uint_as_float(((unsigned)h) << 16);
}
__device__ __forceinline__ void split3(float v, unsigned short& h,
                                       unsigned short& m, unsigned short& l) {
  h = f2bf(v);
  float r = v - bf2f(h);
  m = f2bf(r);
  float r2 = r - bf2f(m);
  l = f2bf(r2);
}

// ---------------------------------------------------------------------------
// Weight split-transform. Wsp[phase=ks*9+tap][mt][split][kg4][oc128][ci8],
// oc' = hid*4+gate; oc low-4 bits XOR-swizzled by kg<<1 (bank stagger).
// ---------------------------------------------------------------------------
__global__ __launch_bounds__(256)
void wsplit(const float* __restrict__ W, unsigned short* __restrict__ Wsp,
            int CTOT, int ci_off, int total)
{
  int i = blockIdx.x * 256 + threadIdx.x;
  if (i >= total) return;
  int ci8 = i & 7;
  int oc  = (i >> 3) & 127;
  int kg  = (i >> 10) & 3;
  int mtl = (i >> 12) & 3;
  int r   = i >> 14;            // phase = ks*9 + tap
  int tap = r % 9;
  int ks  = r / 9;
  int ocp = mtl * 128 + oc;
  int hid = ocp >> 2, gate = ocp & 3;
  int cio = ci_off + ks * 32 + kg * 8 + ci8;
  float v = W[((size_t)(gate * HID_ + hid) * CTOT + cio) * 9 + tap];
  unsigned short h, m, l;
  split3(v, h, m, l);
  int ocs = (oc & 0x70) | ((oc ^ (kg << 1)) & 0x0F);   // bank swizzle
  size_t base = ((size_t)(r * 4 + mtl) * 3) * 4096 + kg * 1024 + ocs * 8 + ci8;
  Wsp[base] = h; Wsp[base + 4096] = m; Wsp[base + 8192] = l;
}

// Layer-0 x-part weights: Wxp[oc'(512)][ci3*9+tap] fp32
__global__ __launch_bounds__(256)
void wtx(const float* __restrict__ W0, float* __restrict__ Wxp)
{
  int i = blockIdx.x * 256 + threadIdx.x;
  if (i >= 512 * 27) return;
  int ocp = i / 27, rem = i % 27;
  int ci = rem / 9, tap = rem % 9;
  int hid = ocp >> 2, gate = ocp & 3;
  Wxp[i] = W0[((size_t)(gate * HID_ + hid) * 131 + ci) * 9 + tap];
}

// ---------------------------------------------------------------------------
// Split-bf16 MFMA fused conv + ConvLSTM. grid (4 mt, 60 nt, n steps), 256 thr.
// M=128 oc' (16 hid x 4 gates x 2 wm), N=64 (2 rows x 32 x).
// ---------------------------------------------------------------------------
struct StepSlot {
  const unsigned short* Wsp;
  const float* Wxp;
  const unsigned short* xs;   // prev-layer hsplit (chunks 0..3) or null
  const unsigned short* hs;   // own hsplit (remaining chunks) or null
  const float* xraw;          // layer0 raw x or null
  const float* bias;
  float* hout; float* cbuf;
  unsigned short* hsout;      // own hsplit out slot
  int nchunk; int is_l0;
};
struct StepArgs { StepSlot s[4]; };

__global__ __launch_bounds__(256, 2)
void conv_mfma(StepArgs args)
{
  const StepSlot sl = args.s[blockIdx.z];
  const int tid = threadIdx.x;
  const int mt = blockIdx.x;            // 0..3
  const int nt = blockIdx.y;            // 0..59
  const int b  = nt / 15;
  const int y0 = (nt % 15) * 2;
  const int lane = tid & 63;
  const int wid = tid >> 6;
  const int wm = wid >> 1;              // 0..1  (M half)
  const int wn = wid & 1;               // 0..1  (row)
  const int lanelo = lane & 15;
  const int kgl = lane >> 4;
  const int lsw = lanelo ^ (kgl << 1);  // A bank-deswizzle

  // sact: [s3][r4][kg4][col34][ci8] = 13056 sh (26112B); sW: 2x12288 sh (49152B)
  __shared__ __align__(16) unsigned short sact[13056];
  __shared__ __align__(16) unsigned short sW[2][12288];

  f32x4 acc[4][2];
  #pragma unroll
  for (int mf = 0; mf < 4; ++mf)
    #pragma unroll
    for (int nf = 0; nf < 2; ++nf)
      acc[mf][nf] = (f32x4){0.f, 0.f, 0.f, 0.f};

  // ---- layer-0 x-part (CIN=3) VALU pass ----
  if (sl.is_l0) {
    float* sWx = (float*)&sW[0][0];     // 13824B scratch
    for (int p = tid; p < 128 * 27; p += 256)
      sWx[p] = sl.Wxp[(size_t)mt * 128 * 27 + p];
    __syncthreads();
    const int y = y0 + wn;
    #pragma unroll
    for (int nf = 0; nf < 2; ++nf) {
      const int x = nf * 16 + lanelo;
      float xw[3][3][3];
      #pragma unroll
      for (int ci = 0; ci < 3; ++ci)
        #pragma unroll
        for (int ky = 0; ky < 3; ++ky)
          #pragma unroll
          for (int kx = 0; kx < 3; ++kx) {
            int yy = y + ky - 1, xx = x + kx - 1;
            xw[ci][ky][kx] = ((unsigned)yy < 30u && (unsigned)xx < 32u)
                ? sl.xraw[((size_t)(b * 3 + ci) * H_ + yy) * W_ + xx] : 0.f;
          }
      #pragma unroll
      for (int mf = 0; mf < 4; ++mf)
        #pragma unroll
        for (int g = 0; g < 4; ++g) {
          int oc = wm * 64 + mf * 16 + (kgl << 2) + g;
          float s = 0.f;
          #pragma unroll
          for (int ci = 0; ci < 3; ++ci)
            #pragma unroll
            for (int kk = 0; kk < 9; ++kk)
              s = fmaf(sWx[oc * 27 + ci * 9 + kk], xw[ci][kk / 3][kk % 3], s);
          acc[mf][nf][g] += s;
        }
    }
    __syncthreads();
  }

  const int NCH = sl.nchunk;

  // flat copy of one chunk's 3 split regions (8704B each) into sact
  auto stageAct = [&](int c) {
    const unsigned short* src; int ch;
    if (sl.xs) { if (c < 4) { src = sl.xs; ch = c; } else { src = sl.hs; ch = c - 4; } }
    else       { src = sl.hs; ch = c; }
    #pragma unroll
    for (int s = 0; s < 3; ++s) {
      const char* g = (const char*)(src + (((size_t)b * 3 + s) * 4 + ch) * HS_CH_
                                    + (size_t)y0 * HS_ROW_);
      char* d = (char*)sact + s * 8704;
      for (int q = tid; q < 544; q += 256)
        *(uint4*)(d + q * 16) = *(const uint4*)(g + q * 16);
    }
  };

  // stage one phase's weights (24576B) via global_load_lds; 6 calls/wave
  auto stageW = [&](int ph, int buf) {
    const char* g = (const char*)(sl.Wsp + ((size_t)ph * 4 + mt) * 12288);
    char* d = (char*)&sW[buf][0];
    const int wb = wid * 6144;
    const int lb = lane * 16;
    #pragma unroll
    for (int q = 0; q < 6; ++q)
      gload16(g + wb + q * 1024 + lb, d + wb + q * 1024);
  };

  if (NCH > 0) {
    stageAct(0);
    stageW(0, 0);
    __syncthreads();
    const int NPH = NCH * 9;
    int ph = 0;
    for (int c = 0; c < NCH; ++c) {
      #pragma unroll
      for (int tap = 0; tap < 9; ++tap, ++ph) {
        if (ph + 1 < NPH) stageW(ph + 1, (ph + 1) & 1);
        const int ky = tap / 3, kx = tap % 3;
        const bs8* Bv = (const bs8*)sact;
        bs8 Bf[3][2];
        #pragma unroll
        for (int s = 0; s < 3; ++s)
          #pragma unroll
          for (int nf = 0; nf < 2; ++nf)
            Bf[s][nf] = Bv[((s * 4 + wn + ky) * 4 + kgl) * 34 + nf * 16 + lanelo + kx];
        const bs8* Aw = (const bs8*)&sW[ph & 1][0];
        #define DOSB(SB)                                                       \
          _Pragma("unroll")                                                    \
          for (int mf = 0; mf < 4; ++mf) {                                     \
            _Pragma("unroll")                                                  \
            for (int nf = 0; nf < 2; ++nf)                                     \
              acc[mf][nf] = __builtin_amdgcn_mfma_f32_16x16x32_bf16(           \
                  Af[mf], Bf[SB][nf], acc[mf][nf], 0, 0, 0);                   \
          }
        {  // sa = 0: products (0,0) (0,1) (0,2)
          bs8 Af[4];
          #pragma unroll
          for (int mf = 0; mf < 4; ++mf)
            Af[mf] = Aw[(0 * 4 + kgl) * 128 + wm * 64 + mf * 16 + lsw];
          DOSB(0) DOSB(1) DOSB(2)
        }
        {  // sa = 1: products (1,0) (1,1)
          bs8 Af[4];
          #pragma unroll
          for (int mf = 0; mf < 4; ++mf)
            Af[mf] = Aw[(1 * 4 + kgl) * 128 + wm * 64 + mf * 16 + lsw];
          DOSB(0) DOSB(1)
        }
        {  // sa = 2: product (2,0)
          bs8 Af[4];
          #pragma unroll
          for (int mf = 0; mf < 4; ++mf)
            Af[mf] = Aw[(2 * 4 + kgl) * 128 + wm * 64 + mf * 16 + lsw];
          DOSB(0)
        }
        #undef DOSB
        __syncthreads();
      }
      if (c + 1 < NCH) {
        stageAct(c + 1);
        __syncthreads();
      }
    }
  }

  // ---- in-register LSTM epilogue ----
  float hv[4][2];
  const int y = y0 + wn;
  #pragma unroll
  for (int mf = 0; mf < 4; ++mf) {
    const int hlo = wm * 16 + mf * 4 + kgl;
    const int hid = mt * 32 + hlo;
    const float b0 = sl.bias[hid];
    const float b1 = sl.bias[128 + hid];
    const float b2 = sl.bias[256 + hid];
    const float b3 = sl.bias[384 + hid];
    #pragma unroll
    for (int nf = 0; nf < 2; ++nf) {
      const int x = nf * 16 + lanelo;
      const size_t idx = ((size_t)(b * HID_ + hid) * H_ + y) * W_ + x;
      float vi = acc[mf][nf][0] + b0;
      float vf = acc[mf][nf][1] + b1;
      float vo = acc[mf][nf][2] + b2;
      float vg = acc[mf][nf][3] + b3;
      float ig = 1.f / (1.f + expf(-vi));
      float fg = 1.f / (1.f + expf(-vf));
      float og = 1.f / (1.f + expf(-vo));
      float gg = tanhf(vg);
      float cn = fg * sl.cbuf[idx] + ig * gg;
      sl.cbuf[idx] = cn;
      float hn = og * tanhf(cn);
      sl.hout[idx] = hn;
      hv[mf][nf] = hn;
    }
  }

  // ---- split h and store to fragment-ready global layout ----
  if (sl.hsout) {
    unsigned short* hl = sact;          // reuse: [s3][r2][kg4][x32][cl8] = 6144
    #pragma unroll
    for (int mf = 0; mf < 4; ++mf) {
      const int hlo = wm * 16 + mf * 4 + kgl;
      const int kg = hlo >> 3, cl = hlo & 7;
      #pragma unroll
      for (int nf = 0; nf < 2; ++nf) {
        unsigned short hh, hm, hlw;
        split3(hv[mf][nf], hh, hm, hlw);
        const int x = nf * 16 + lanelo;
        int o = ((wn * 4 + kg) * 32 + x) * 8 + cl;
        hl[o] = hh; hl[o + 2048] = hm; hl[o + 4096] = hlw;
      }
    }
    __syncthreads();
    for (int q = tid; q < 768; q += 256) {
      int s = q >> 8, rem = q & 255;
      int r = rem >> 7, kg = (rem >> 5) & 3, x = rem & 31;
      uint4 v = *(const uint4*)&hl[(((s * 2 + r) * 4 + kg) * 32 + x) * 8];
      unsigned short* dst = sl.hsout
          + ((((size_t)b * 3 + s) * 4 + mt) * 32 + (y0 + r + 1)) * HS_ROW_
          + (kg * 34 + x + 1) * 8;
      *(uint4*)dst = v;
    }
  }
}

// ---------------------------------------------------------------------------
// lin1 split-K + finish + lin2 (unchanged)
// ---------------------------------------------------------------------------
__global__ __launch_bounds__(256)
void lin1_part(const float* __restrict__ h, const float* __restrict__ w,
               float* __restrict__ part)
{
  const int bid = blockIdx.x;
  const int o  = bid >> 3;
  const int ks = bid & 7;
  const int tid = threadIdx.x;
  const float4* w4 = (const float4*)(w + (size_t)o * LIN1_IN_) + ks * 3840;
  const float4* h4 = (const float4*)h + ks * 3840;
  float acc[4] = {0.f, 0.f, 0.f, 0.f};
  for (int i = tid; i < 3840; i += 256) {
    float4 wv = w4[i];
    #pragma unroll
    for (int b = 0; b < 4; ++b) {
      float4 hv = h4[(size_t)b * 30720 + i];
      acc[b] = fmaf(wv.x, hv.x, fmaf(wv.y, hv.y,
               fmaf(wv.z, hv.z, fmaf(wv.w, hv.w, acc[b]))));
    }
  }
  #pragma unroll
  for (int b = 0; b < 4; ++b)
    for (int m = 32; m; m >>= 1) acc[b] += __shfl_xor(acc[b], m);
  __shared__ float red[4][4];
  if ((tid & 63) == 0) {
    #pragma unroll
    for (int b = 0; b < 4; ++b) red[tid >> 6][b] = acc[b];
  }
  __syncthreads();
  if (tid == 0) {
    #pragma unroll
    for (int b = 0; b < 4; ++b) {
      float s = red[0][b] + red[1][b] + red[2][b] + red[3][b];
      part[((size_t)b * 256 + o) * 8 + ks] = s;
    }
  }
}

__global__ __launch_bounds__(256)
void lin1_finish(const float* __restrict__ part, const float* __restrict__ bias,
                 float* __restrict__ z1)
{
  int i = blockIdx.x * 256 + threadIdx.x;
  if (i < 1024) {
    int o = i & 255;
    float s = bias[o];
    #pragma unroll
    for (int k = 0; k < 8; ++k) s += part[(size_t)i * 8 + k];
    z1[i] = fmaxf(s, 0.f);
  }
}

__global__ __launch_bounds__(64)
void lin2_kernel(const float* __restrict__ z1, const float* __restrict__ w2,
                 const float* __restrict__ b2, float* __restrict__ out)
{
  const int lane = threadIdx.x;
  for (int p = 0; p < 8; ++p) {
    int j = p >> 2, b = p & 3;
    float acc = 0.f;
    for (int k = lane; k < 256; k += 64)
      acc = fmaf(z1[b * 256 + k], w2[j * 256 + k], acc);
    for (int m = 32; m; m >>= 1) acc += __shfl_xor(acc, m);
    if (lane == 0) out[p] = acc + b2[j];
  }
}

extern "C" void kernel_launch(void* const* d_in, const int* in_sizes, int n_in,
                              void* d_out, int out_size, void* d_ws, size_t ws_size,
                              hipStream_t stream) {
  const float* x = (const float*)d_in[0];
  const float* Wks[4] = {(const float*)d_in[1], (const float*)d_in[3],
                         (const float*)d_in[5], (const float*)d_in[7]};
  const float* bks[4] = {(const float*)d_in[2], (const float*)d_in[4],
                         (const float*)d_in[6], (const float*)d_in[8]};
  const float* lin1_w = (const float*)d_in[9];
  const float* lin1_b = (const float*)d_in[10];
  const float* lin2_w = (const float*)d_in[11];
  const float* lin2_b = (const float*)d_in[12];
  float* out = (float*)d_out;

  const int CTOTs[4] = {131, 256, 256, 256};
  const int NKS[4]   = {4, 8, 8, 8};

  // ---- workspace carve: bf16 regions first, then fp32 ----
  unsigned short* up = (unsigned short*)d_ws;
  unsigned short* wsp[4];
  for (int l = 0; l < 4; ++l) {
    wsp[l] = up;
    up += (size_t)NKS[l] * 9 * 4 * 3 * 4096;
  }
  unsigned short* hsr0 = up;            // 8 slots, contiguous
  unsigned short* hsr[4];
  for (int l = 0; l < 4; ++l) { hsr[l] = up; up += 2 * (size_t)HS_SLOT_; }
  float* fp = (float*)up;
  float* wxp = fp;   fp += 512 * 27;
  float* houtb[4];
  for (int l = 0; l < 4; ++l) { houtb[l] = fp; fp += BCHW_; }
  float* cbase = fp; fp += 4 * BCHW_;
  float* part = fp;  fp += 4 * 256 * 8;
  float* z1 = fp;    fp += 1024;

  // ---- one-time weight transforms ----
  wtx<<<dim3(54), dim3(256), 0, stream>>>(Wks[0], wxp);
  for (int l = 0; l < 4; ++l) {
    int total = NKS[l] * 9 * 4 * 4096;
    wsplit<<<dim3((total + 255) / 256), dim3(256), 0, stream>>>(
        Wks[l], wsp[l], CTOTs[l], (l == 0) ? 3 : 0, total);
  }
  // zero c buffers and ALL hsplit rings (halo rows/cols must be 0)
  hipMemsetAsync(cbase, 0, 4 * BCHW_ * sizeof(float), stream);
  hipMemsetAsync(hsr0, 0, 8 * (size_t)HS_SLOT_ * sizeof(unsigned short), stream);

  // ---- diagonal wavefront over (layer, t) ----
  for (int d = 0; d <= 10; ++d) {
    StepArgs a;
    int n = 0;
    for (int l = 0; l < 4; ++l) {
      int t = d - l;
      if (t < 0 || t > 7) continue;
      StepSlot& s = a.s[n++];
      s.is_l0 = (l == 0);
      s.Wsp = wsp[l];
      s.Wxp = (l == 0) ? wxp : nullptr;
      s.xraw = (l == 0) ? x + (size_t)t * B_ * CIN_ * NPOS_ : nullptr;
      s.xs = (l == 0) ? nullptr : hsr[l - 1] + (size_t)(t & 1) * HS_SLOT_;
      s.hs = (t == 0) ? nullptr : hsr[l] + (size_t)((t - 1) & 1) * HS_SLOT_;
      s.bias = bks[l];
      s.hout = houtb[l];
      s.cbuf = cbase + (size_t)l * BCHW_;
      s.hsout = hsr[l] + (size_t)(t & 1) * HS_SLOT_;
      s.nchunk = (l == 0) ? (t ? 4 : 0) : (t ? 8 : 4);
    }
    for (int z = n; z < 4; ++z) a.s[z] = a.s[0];
    conv_mfma<<<dim3(4, 60, n), dim3(256), 0, stream>>>(a);
  }

  lin1_part<<<dim3(2048), dim3(256), 0, stream>>>(houtb[3], lin1_w, part);
  lin1_finish<<<dim3(4), dim3(256), 0, stream>>>(part, lin1_b, z1);
  lin2_kernel<<<dim3(1), dim3(64), 0, stream>>>(z1, lin2_w, lin2_b, out);
}